// Round 9
// baseline (525.978 us; speedup 1.0000x reference)
//
#include <hip/hip_runtime.h>
#include <hip/hip_cooperative_groups.h>

namespace cg = cooperative_groups;

// InteractionNetwork B=4, N=256, D=128, L=3.
// agg = (sum_j adj_ij * relu(xi_i + xj_j)) @ ew2 + rowsum(adj)_i * eb2  (eb1 folded into xi)
// R8 lesson: dispatch-count reduction 7->4 changed NOTHING (145->149us); per-layer cost
// pinned ~34us across 3 structures -> serialization/ramp between dispatches, not count.
// R9: SINGLE cooperative dispatch. Block owns rows r0,r0+1 for the entire network:
// x in LDS across layers, xi in regs, adj staged once. Only xj crosses blocks ->
// double-buffered global + 3 grid.sync()s. threadfence for cross-XCD visibility.

#define DD 128
#define NN 256

__global__ __launch_bounds__(256, 4) void kmega(
    const float* __restrict__ x0, const float* __restrict__ adj,
    const float* __restrict__ ew1, const float* __restrict__ eb1,
    const float* __restrict__ ew2, const float* __restrict__ eb2,
    const float* __restrict__ nw1, const float* __restrict__ nb1,
    const float* __restrict__ nw2, const float* __restrict__ nb2,
    float* __restrict__ out, float* xj0, float* xj1)
{
  cg::grid_group grid = cg::this_grid();
  const int r0 = blockIdx.x * 2;      // rows never straddle a batch
  const int b  = r0 >> 8;
  const int t = threadIdx.x, c = t & 127, hh = t >> 7;

  __shared__ float2 adj2[NN];         // [j] -> (row0, row1), staged once
  __shared__ float xs[2][DD], hs[2][DD], ags[2][DD], ns[2][DD];
  __shared__ float red[2][2][2][DD];  // [stream][row][hh][c]
  __shared__ float rs[2];

  // ---- stage adj rows + x rows (once)
  {
    const float* ap = adj + (size_t)r0 * NN;
    adj2[t].x = ap[t];
    adj2[t].y = ap[NN + t];
    ((float*)xs)[t] = x0[r0 * DD + t];
  }
  __syncthreads();

  // ---- rowsum (once; adj constant across layers)
  {
    const int wv = t >> 6, lane = t & 63;
    if (wv < 2) {
      float s;
      if (wv == 0) s = adj2[lane].x + adj2[lane + 64].x + adj2[lane + 128].x + adj2[lane + 192].x;
      else         s = adj2[lane].y + adj2[lane + 64].y + adj2[lane + 128].y + adj2[lane + 192].y;
      for (int off = 32; off; off >>= 1) s += __shfl_down(s, off);
      if (lane == 0) rs[wv] = s;
    }
  }

  // ---- Phase P: layer-0 projection from xs; xi -> regs, xj -> global
  float xiv0, xiv1;
  {
    float ai[2] = {0.f, 0.f}, aj[2] = {0.f, 0.f};
    const int k0 = hh * 64;
#pragma unroll 8
    for (int kk = 0; kk < 64; ++kk) {
      const int k = k0 + kk;
      const float wiv = ew1[k * DD + c], wjv = ew1[(DD + k) * DD + c];
      ai[0] = fmaf(xs[0][k], wiv, ai[0]); ai[1] = fmaf(xs[1][k], wiv, ai[1]);
      aj[0] = fmaf(xs[0][k], wjv, aj[0]); aj[1] = fmaf(xs[1][k], wjv, aj[1]);
    }
    red[0][0][hh][c] = ai[0]; red[0][1][hh][c] = ai[1];
    red[1][0][hh][c] = aj[0]; red[1][1][hh][c] = aj[1];
  }
  __syncthreads();
  {
    const float bv = eb1[c];
    xiv0 = red[0][0][0][c] + red[0][0][1][c] + bv;
    xiv1 = red[0][1][0][c] + red[0][1][1][c] + bv;
    xj0[(r0 + hh) * DD + c] = red[1][hh][0][c] + red[1][hh][1][c];
  }
  __threadfence();
  grid.sync();

#pragma unroll
  for (int l = 0; l < 3; ++l) {
    const float* xjr = (l & 1) ? xj1 : xj0;
    float*       xjw = (l & 1) ? xj0 : xj1;
    const float* ew2l = ew2 + l * DD * DD;
    const float* eb2l = eb2 + l * DD;
    const float* nw1l = nw1 + l * 2 * DD * DD;
    const float* nb1l = nb1 + l * DD;
    const float* nw2l = nw2 + l * DD * DD;
    const float* nb2l = nb2 + l * DD;

    // ---- agg: thread (c, j-half hh) partial over 128 j for both rows
    {
      float acc0 = 0.f, acc1 = 0.f;
      const float* xjp = xjr + (size_t)(b * NN + hh * 128) * DD + c;
#pragma unroll 8
      for (int jj = 0; jj < 128; ++jj) {
        const float xv = xjp[(size_t)jj * DD];
        const float2 av = adj2[hh * 128 + jj];
        acc0 = fmaf(av.x, fmaxf(xiv0 + xv, 0.f), acc0);
        acc1 = fmaf(av.y, fmaxf(xiv1 + xv, 0.f), acc1);
      }
      red[0][0][hh][c] = acc0; red[0][1][hh][c] = acc1;
    }
    __syncthreads();
    { const int r = hh; hs[r][c] = red[0][r][0][c] + red[0][r][1][c]; }
    __syncthreads();

    // ---- A: a1 = hs@ew2 (-> ags) ; a2 = xs@nw1a (regs, for B)
    float a2[2] = {0.f, 0.f};
    {
      float a1[2] = {0.f, 0.f};
      const int k0 = hh * 64;
#pragma unroll 8
      for (int kk = 0; kk < 64; ++kk) {
        const int k = k0 + kk;
        const float w2v = ew2l[k * DD + c], wav = nw1l[k * DD + c];
        a1[0] = fmaf(hs[0][k], w2v, a1[0]); a1[1] = fmaf(hs[1][k], w2v, a1[1]);
        a2[0] = fmaf(xs[0][k], wav, a2[0]); a2[1] = fmaf(xs[1][k], wav, a2[1]);
      }
      red[0][0][hh][c] = a1[0]; red[0][1][hh][c] = a1[1];
    }
    __syncthreads();
    { const int r = hh;
      ags[r][c] = red[0][r][0][c] + red[0][r][1][c] + rs[r] * eb2l[c]; }
    __syncthreads();

    // ---- B: a3 = ags@nw1b ; ns = relu(a2 + a3 + nb1)
    {
      float a3[2] = {0.f, 0.f};
      const int k0 = hh * 64;
#pragma unroll 8
      for (int kk = 0; kk < 64; ++kk) {
        const int k = k0 + kk;
        const float wbv = nw1l[(DD + k) * DD + c];
        a3[0] = fmaf(ags[0][k], wbv, a3[0]); a3[1] = fmaf(ags[1][k], wbv, a3[1]);
      }
      red[0][0][hh][c] = a2[0] + a3[0]; red[0][1][hh][c] = a2[1] + a3[1];
    }
    __syncthreads();
    { const int r = hh;
      ns[r][c] = fmaxf(red[0][r][0][c] + red[0][r][1][c] + nb1l[c], 0.f); }
    __syncthreads();

    // ---- C: upd = ns@nw2 ; xo = x + upd + nb2 ; l<2: xs<-xo, l==2: out<-xo
    {
      float a4[2] = {0.f, 0.f};
      const int k0 = hh * 64;
#pragma unroll 8
      for (int kk = 0; kk < 64; ++kk) {
        const int k = k0 + kk;
        const float wv = nw2l[k * DD + c];
        a4[0] = fmaf(ns[0][k], wv, a4[0]); a4[1] = fmaf(ns[1][k], wv, a4[1]);
      }
      red[0][0][hh][c] = a4[0]; red[0][1][hh][c] = a4[1];
    }
    __syncthreads();
    { const int r = hh;
      const float xo = xs[r][c] + red[0][r][0][c] + red[0][r][1][c] + nb2l[c];
      if (l == 2) out[(r0 + r) * DD + c] = xo;
      else        xs[r][c] = xo;
    }
    if (l == 2) return;
    __syncthreads();

    // ---- D: next-layer projection from updated xs; xi -> regs, xj -> global
    {
      const float* ew1n = ew1 + (l + 1) * 2 * DD * DD;
      float ai[2] = {0.f, 0.f}, aj[2] = {0.f, 0.f};
      const int k0 = hh * 64;
#pragma unroll 8
      for (int kk = 0; kk < 64; ++kk) {
        const int k = k0 + kk;
        const float wiv = ew1n[k * DD + c], wjv = ew1n[(DD + k) * DD + c];
        ai[0] = fmaf(xs[0][k], wiv, ai[0]); ai[1] = fmaf(xs[1][k], wiv, ai[1]);
        aj[0] = fmaf(xs[0][k], wjv, aj[0]); aj[1] = fmaf(xs[1][k], wjv, aj[1]);
      }
      red[0][0][hh][c] = ai[0]; red[0][1][hh][c] = ai[1];
      red[1][0][hh][c] = aj[0]; red[1][1][hh][c] = aj[1];
    }
    __syncthreads();
    {
      const float bv = eb1[(l + 1) * DD + c];
      xiv0 = red[0][0][0][c] + red[0][0][1][c] + bv;
      xiv1 = red[0][1][0][c] + red[0][1][1][c] + bv;
      xjw[(r0 + hh) * DD + c] = red[1][hh][0][c] + red[1][hh][1][c];
    }
    __threadfence();
    grid.sync();
  }
}

extern "C" void kernel_launch(void* const* d_in, const int* in_sizes, int n_in,
                              void* d_out, int out_size, void* d_ws, size_t ws_size,
                              hipStream_t stream) {
  const float* x0  = (const float*)d_in[0];
  const float* adj = (const float*)d_in[1];
  const float* ew1 = (const float*)d_in[2];
  const float* eb1 = (const float*)d_in[3];
  const float* ew2 = (const float*)d_in[4];
  const float* eb2 = (const float*)d_in[5];
  const float* nw1 = (const float*)d_in[6];
  const float* nb1 = (const float*)d_in[7];
  const float* nw2 = (const float*)d_in[8];
  const float* nb2 = (const float*)d_in[9];
  float* out = (float*)d_out;
  float* ws  = (float*)d_ws;

  float* xj0 = ws;            // 131072 floats each
  float* xj1 = ws + 131072;

  void* args[] = {
    (void*)&x0, (void*)&adj, (void*)&ew1, (void*)&eb1, (void*)&ew2, (void*)&eb2,
    (void*)&nw1, (void*)&nb1, (void*)&nw2, (void*)&nb2, (void*)&out,
    (void*)&xj0, (void*)&xj1
  };
  hipLaunchCooperativeKernel((void*)kmega, dim3(512), dim3(256), args, 0, stream);
}

// Round 10
// 197.290 us; speedup vs baseline: 2.6660x; 2.6660x over previous
//
#include <hip/hip_runtime.h>

// InteractionNetwork B=4, N=256, D=128, L=3.
// agg = (sum_j adj_ij * relu(xi_i + xj_j)) @ ew2 + rowsum(adj)_i * eb2  (eb1 folded into xi)
// R9 lesson: grid.sync ~140us each on MI355X (atomic spin, 22MB coherence writes) -> dead.
// R10: 4 dispatches (R8 skeleton) + latency fix: stage each weight matrix into LDS via
// coalesced float4 loads, software-pipelined (issue after barrier, compute, drain under
// compute at next barrier). 512 thr/block, 4 rows/block, grid 256 (1 block/CU, 148KB LDS).

#define DD 128
#define NN 256

// ---------------- kproj (unchanged from R8): grid 512, block 256; 2 rows/block
__global__ __launch_bounds__(256, 4) void kproj(
    const float* __restrict__ x, const float* __restrict__ w,
    const float* __restrict__ b1, float* __restrict__ xi, float* __restrict__ xj)
{
  const int r0 = blockIdx.x * 2;
  const int t = threadIdx.x, c = t & 127, hh = t >> 7;
  __shared__ float xs[2][DD];
  __shared__ float red[2][2][2][DD];
  ((float*)xs)[t] = x[r0 * DD + t];
  __syncthreads();
  float ai[2] = {0.f, 0.f}, aj[2] = {0.f, 0.f};
  const int k0 = hh * 64;
#pragma unroll 8
  for (int kk = 0; kk < 64; ++kk) {
    const int k = k0 + kk;
    const float wiv = w[k * DD + c], wjv = w[(DD + k) * DD + c];
    ai[0] = fmaf(xs[0][k], wiv, ai[0]); ai[1] = fmaf(xs[1][k], wiv, ai[1]);
    aj[0] = fmaf(xs[0][k], wjv, aj[0]); aj[1] = fmaf(xs[1][k], wjv, aj[1]);
  }
  red[0][0][hh][c] = ai[0]; red[0][1][hh][c] = ai[1];
  red[1][0][hh][c] = aj[0]; red[1][1][hh][c] = aj[1];
  __syncthreads();
  const int g = hh;
#pragma unroll
  for (int r = 0; r < 2; ++r) {
    const float s = red[g][r][0][c] + red[g][r][1][c];
    if (g == 0) xi[(r0 + r) * DD + c] = s + b1[c];
    else        xj[(r0 + r) * DD + c] = s;
  }
}

// one k-quarter (32-wide) of a [4 rows x 128] @ [128 x 128] partial, LDS weights
__device__ __forceinline__ void mm4(const float in[4][DD], const float* wb,
                                    int k0, int c, float a[4]) {
#pragma unroll
  for (int kq = 0; kq < 8; ++kq) {
    const int k = k0 + kq * 4;
    const float4 i0 = *(const float4*)&in[0][k];
    const float4 i1 = *(const float4*)&in[1][k];
    const float4 i2 = *(const float4*)&in[2][k];
    const float4 i3 = *(const float4*)&in[3][k];
    const float* p0 = (const float*)&i0;
    const float* p1 = (const float*)&i1;
    const float* p2 = (const float*)&i2;
    const float* p3 = (const float*)&i3;
#pragma unroll
    for (int q = 0; q < 4; ++q) {
      const float wv = wb[(k + q) * DD + c];
      a[0] = fmaf(p0[q], wv, a[0]);
      a[1] = fmaf(p1[q], wv, a[1]);
      a[2] = fmaf(p2[q], wv, a[2]);
      a[3] = fmaf(p3[q], wv, a[3]);
    }
  }
}

// ---------------- klayer: grid 256, block 512; block owns 4 rows end-to-end.
__global__ __launch_bounds__(512, 2) void klayer(
    const float* __restrict__ xin, const float* __restrict__ adj,
    const float* __restrict__ xi, const float* __restrict__ xj,
    const float* __restrict__ ew2, const float* __restrict__ eb2,
    const float* __restrict__ nw1, const float* __restrict__ nb1,
    const float* __restrict__ nw2, const float* __restrict__ nb2,
    float* __restrict__ xout,
    const float* __restrict__ ew1n, const float* __restrict__ eb1n,
    float* __restrict__ xin_, float* __restrict__ xjn, const int has_next)
{
  const int r0 = blockIdx.x * 4;     // rows never straddle a batch
  const int b  = r0 >> 8;
  const int t = threadIdx.x, c = t & 127, g = t >> 7;  // g: k-quarter / row group
  const int k0 = g * 32;

  __shared__ float wbuf[2 * DD * DD];   // 128 KB staged weights (1 or 2 matrices)
  __shared__ float adjs[4][NN];         // 4 KB
  __shared__ float xs[4][DD], hs[4][DD], ags[4][DD], ns[4][DD];
  __shared__ float red[4][4][DD];       // [row][group][c] 8 KB
  __shared__ float rs[4];

  float4 w8[16];

  // issue ew2 stage loads (8 f4/thread) -- land during agg
#pragma unroll
  for (int i = 0; i < 8; ++i) w8[i] = ((const float4*)ew2)[t + i * 512];

  // stage adj (threads 0-255) + x (threads 256-383), coalesced float4
  if (t < 256)      ((float4*)adjs)[t]     = ((const float4*)(adj + (size_t)r0 * NN))[t];
  else if (t < 384) ((float4*)xs)[t - 256] = ((const float4*)(xin + (size_t)r0 * DD))[t - 256];

  float xiv[4];
#pragma unroll
  for (int r = 0; r < 4; ++r) xiv[r] = xi[(size_t)(r0 + r) * DD + c];
  __syncthreads();

  // rowsum (waves 0..3 -> rows 0..3); adj constant across phases
  {
    const int w = t >> 6, lane = t & 63;
    if (w < 4) {
      float s = adjs[w][lane] + adjs[w][lane + 64] + adjs[w][lane + 128] + adjs[w][lane + 192];
#pragma unroll
      for (int off = 32; off; off >>= 1) s += __shfl_down(s, off);
      if (lane == 0) rs[w] = s;
    }
  }

  // agg: group g covers j in [64g, 64g+64); 64 independent L2 loads in flight
  {
    float acc[4] = {0.f, 0.f, 0.f, 0.f};
    const float* xjp = xj + ((size_t)b * NN + g * 64) * DD + c;
#pragma unroll
    for (int jj = 0; jj < 64; ++jj) {
      const float xv = xjp[(size_t)jj * DD];
#pragma unroll
      for (int r = 0; r < 4; ++r)
        acc[r] = fmaf(adjs[r][g * 64 + jj], fmaxf(xiv[r] + xv, 0.f), acc[r]);
    }
#pragma unroll
    for (int r = 0; r < 4; ++r) red[r][g][c] = acc[r];
  }
  __syncthreads();
  hs[g][c] = red[g][0][c] + red[g][1][c] + red[g][2][c] + red[g][3][c];
#pragma unroll
  for (int i = 0; i < 8; ++i) ((float4*)wbuf)[t + i * 512] = w8[i];   // ew2 -> LDS
  __syncthreads();

  // ---- P1: ags = hs@ew2 + rs*eb2 ; issue nw1 (16 f4)
#pragma unroll
  for (int i = 0; i < 16; ++i) w8[i] = ((const float4*)nw1)[t + i * 512];
  {
    float a[4] = {0.f, 0.f, 0.f, 0.f};
    mm4(hs, wbuf, k0, c, a);
#pragma unroll
    for (int r = 0; r < 4; ++r) red[r][g][c] = a[r];
  }
  __syncthreads();
  ags[g][c] = red[g][0][c] + red[g][1][c] + red[g][2][c] + red[g][3][c] + rs[g] * eb2[c];
#pragma unroll
  for (int i = 0; i < 16; ++i) ((float4*)wbuf)[t + i * 512] = w8[i];  // nw1 -> LDS
  __syncthreads();

  // ---- P23: ns = relu(xs@nw1a + ags@nw1b + nb1) ; issue nw2 (8 f4)
#pragma unroll
  for (int i = 0; i < 8; ++i) w8[i] = ((const float4*)nw2)[t + i * 512];
  {
    float a[4] = {0.f, 0.f, 0.f, 0.f};
    mm4(xs,  wbuf,            k0, c, a);
    mm4(ags, wbuf + DD * DD,  k0, c, a);
#pragma unroll
    for (int r = 0; r < 4; ++r) red[r][g][c] = a[r];
  }
  __syncthreads();
  ns[g][c] = fmaxf(red[g][0][c] + red[g][1][c] + red[g][2][c] + red[g][3][c] + nb1[c], 0.f);
#pragma unroll
  for (int i = 0; i < 8; ++i) ((float4*)wbuf)[t + i * 512] = w8[i];   // nw2 -> LDS
  __syncthreads();

  // ---- P4: x' = x + ns@nw2 + nb2 ; issue ew1n (16 f4) if needed
  if (has_next) {
#pragma unroll
    for (int i = 0; i < 16; ++i) w8[i] = ((const float4*)ew1n)[t + i * 512];
  }
  {
    float a[4] = {0.f, 0.f, 0.f, 0.f};
    mm4(ns, wbuf, k0, c, a);
#pragma unroll
    for (int r = 0; r < 4; ++r) red[r][g][c] = a[r];
  }
  __syncthreads();
  {
    const float xnew = xs[g][c] + red[g][0][c] + red[g][1][c] + red[g][2][c] + red[g][3][c] + nb2[c];
    xout[(size_t)(r0 + g) * DD + c] = xnew;
    if (has_next) xs[g][c] = xnew;
  }
  if (!has_next) return;
#pragma unroll
  for (int i = 0; i < 16; ++i) ((float4*)wbuf)[t + i * 512] = w8[i];  // ew1n -> LDS
  __syncthreads();

  // ---- P5: xi_next = x'@ew1n_a + eb1n
  {
    float a[4] = {0.f, 0.f, 0.f, 0.f};
    mm4(xs, wbuf, k0, c, a);
#pragma unroll
    for (int r = 0; r < 4; ++r) red[r][g][c] = a[r];
  }
  __syncthreads();
  xin_[(size_t)(r0 + g) * DD + c] =
      red[g][0][c] + red[g][1][c] + red[g][2][c] + red[g][3][c] + eb1n[c];
  __syncthreads();   // WAR: red re-written by P6

  // ---- P6: xj_next = x'@ew1n_b
  {
    float a[4] = {0.f, 0.f, 0.f, 0.f};
    mm4(xs, wbuf + DD * DD, k0, c, a);
#pragma unroll
    for (int r = 0; r < 4; ++r) red[r][g][c] = a[r];
  }
  __syncthreads();
  xjn[(size_t)(r0 + g) * DD + c] =
      red[g][0][c] + red[g][1][c] + red[g][2][c] + red[g][3][c];
}

extern "C" void kernel_launch(void* const* d_in, const int* in_sizes, int n_in,
                              void* d_out, int out_size, void* d_ws, size_t ws_size,
                              hipStream_t stream) {
  const float* x0  = (const float*)d_in[0];
  const float* adj = (const float*)d_in[1];
  const float* ew1 = (const float*)d_in[2];
  const float* eb1 = (const float*)d_in[3];
  const float* ew2 = (const float*)d_in[4];
  const float* eb2 = (const float*)d_in[5];
  const float* nw1 = (const float*)d_in[6];
  const float* nb1 = (const float*)d_in[7];
  const float* nw2 = (const float*)d_in[8];
  const float* nb2 = (const float*)d_in[9];
  float* out = (float*)d_out;
  float* ws  = (float*)d_ws;

  float* xi0 = ws;                // 131072 floats each
  float* xj0 = ws + 131072;
  float* xi1 = ws + 262144;
  float* xj1 = ws + 393216;
  float* xA  = ws + 524288;
  float* xB  = ws + 655360;

  kproj<<<512, 256, 0, stream>>>(x0, ew1, eb1, xi0, xj0);

  const float* xins[3]  = {x0, xA, xB};
  float*       xouts[3] = {xA, xB, out};
  float*       xis[2] = {xi0, xi1};
  float*       xjs[2] = {xj0, xj1};
  for (int l = 0; l < 3; ++l) {
    const int cur = l & 1, nxt = cur ^ 1;
    const int ln = (l + 1 < 3) ? (l + 1) : 0;  // dummy for last layer (unused)
    klayer<<<256, 512, 0, stream>>>(
        xins[l], adj, xis[cur], xjs[cur],
        ew2 + l * DD * DD, eb2 + l * DD,
        nw1 + l * 2 * DD * DD, nb1 + l * DD,
        nw2 + l * DD * DD, nb2 + l * DD,
        xouts[l],
        ew1 + ln * 2 * DD * DD, eb1 + ln * DD,
        xis[nxt], xjs[nxt], (l + 1 < 3) ? 1 : 0);
  }
}

// Round 14
// 122.121 us; speedup vs baseline: 4.3070x; 1.6155x over previous
//
#include <hip/hip_runtime.h>

// InteractionNetwork B=4, N=256, D=128, L=3.
// agg = (sum_j adj_ij * relu(xi_i + xj_j)) @ ew2 + rowsum(adj)_i * eb2  (eb1 folded into xi)
// R10 lesson: w8[16] staging array -> SCRATCH (96MB HBM writes/dispatch, klayer 45us).
// R11: same 4-dispatch skeleton; weights staged to LDS in SEQUENTIAL phases with
// transient 8xfloat4 (no live range across compute -> no spill). One 64KB W buffer;
// nw1/ew1n staged as two halves. stage->bar->compute; ~14 bars/klayer.

#define DD 128
#define NN 256

// stage one 64KB [128][128] f32 matrix into LDS W; 512 threads x 8 float4, transient.
#define STAGE(SRC) do { \
  const float4* _sp = (const float4*)(SRC); \
  float4* _wp = (float4*)W; \
  float4 _v0=_sp[t], _v1=_sp[t+512], _v2=_sp[t+1024], _v3=_sp[t+1536], \
         _v4=_sp[t+2048], _v5=_sp[t+2560], _v6=_sp[t+3072], _v7=_sp[t+3584]; \
  _wp[t]=_v0; _wp[t+512]=_v1; _wp[t+1024]=_v2; _wp[t+1536]=_v3; \
  _wp[t+2048]=_v4; _wp[t+2560]=_v5; _wp[t+3072]=_v6; _wp[t+3584]=_v7; \
} while (0)

#define RED4 (red[g][0][c] + red[g][1][c] + red[g][2][c] + red[g][3][c])

// one k-quarter (32-wide) of [4 rows x 128] @ [128 x 128], weights in LDS
__device__ __forceinline__ void mm4(const float in[4][DD], const float* W,
                                    int k0, int c, float a[4]) {
#pragma unroll
  for (int kq = 0; kq < 8; ++kq) {
    const int k = k0 + kq * 4;
    const float4 i0 = *(const float4*)&in[0][k];
    const float4 i1 = *(const float4*)&in[1][k];
    const float4 i2 = *(const float4*)&in[2][k];
    const float4 i3 = *(const float4*)&in[3][k];
    const float* p0 = (const float*)&i0;
    const float* p1 = (const float*)&i1;
    const float* p2 = (const float*)&i2;
    const float* p3 = (const float*)&i3;
#pragma unroll
    for (int q = 0; q < 4; ++q) {
      const float wv = W[(k + q) * DD + c];
      a[0] = fmaf(p0[q], wv, a[0]);
      a[1] = fmaf(p1[q], wv, a[1]);
      a[2] = fmaf(p2[q], wv, a[2]);
      a[3] = fmaf(p3[q], wv, a[3]);
    }
  }
}

// ---------------- kproj: grid 256, block 512; 4 rows/block; LDS-staged weights
__global__ __launch_bounds__(512) void kproj(
    const float* __restrict__ x, const float* __restrict__ w,
    const float* __restrict__ b1, float* __restrict__ xi, float* __restrict__ xj)
{
  const int r0 = blockIdx.x * 4;
  const int t = threadIdx.x, c = t & 127, g = t >> 7, k0 = g * 32;
  __shared__ float W[DD * DD];
  __shared__ float xs[4][DD];
  __shared__ float red[4][4][DD];

  STAGE(w);
  if (t < 128) ((float4*)xs)[t] = ((const float4*)(x + (size_t)r0 * DD))[t];
  __syncthreads();

  { float a[4] = {0.f,0.f,0.f,0.f};
    mm4(xs, W, k0, c, a);
#pragma unroll
    for (int r = 0; r < 4; ++r) red[r][g][c] = a[r]; }
  __syncthreads();
  xi[(size_t)(r0 + g) * DD + c] = RED4 + b1[c];
  STAGE(w + DD * DD);
  __syncthreads();

  { float a[4] = {0.f,0.f,0.f,0.f};
    mm4(xs, W, k0, c, a);
#pragma unroll
    for (int r = 0; r < 4; ++r) red[r][g][c] = a[r]; }
  __syncthreads();
  xj[(size_t)(r0 + g) * DD + c] = RED4;
}

// ---------------- klayer: grid 256, block 512; block owns 4 rows end-to-end.
__global__ __launch_bounds__(512) void klayer(
    const float* __restrict__ xin, const float* __restrict__ adj,
    const float* __restrict__ xi, const float* __restrict__ xj,
    const float* __restrict__ ew2, const float* __restrict__ eb2,
    const float* __restrict__ nw1, const float* __restrict__ nb1,
    const float* __restrict__ nw2, const float* __restrict__ nb2,
    float* __restrict__ xout,
    const float* __restrict__ ew1n, const float* __restrict__ eb1n,
    float* __restrict__ xin_, float* __restrict__ xjn, const int has_next)
{
  const int r0 = blockIdx.x * 4;     // rows never straddle a batch
  const int b  = r0 >> 8;
  const int t = threadIdx.x, c = t & 127, g = t >> 7, k0 = g * 32;

  __shared__ float W[DD * DD];          // 64 KB, one staged matrix at a time
  __shared__ float adjs[4][NN];
  __shared__ float xs[4][DD], hs[4][DD], ags[4][DD], ns[4][DD], os[4][DD];
  __shared__ float red[4][4][DD];
  __shared__ float rs[4];

  // ---- S0: stage ew2 + adj + x; xi -> regs
  STAGE(ew2);
  if (t < 256)      ((float4*)adjs)[t]     = ((const float4*)(adj + (size_t)r0 * NN))[t];
  else if (t < 384) ((float4*)xs)[t - 256] = ((const float4*)(xin + (size_t)r0 * DD))[t - 256];
  float xiv[4];
#pragma unroll
  for (int r = 0; r < 4; ++r) xiv[r] = xi[(size_t)(r0 + r) * DD + c];
  __syncthreads();

  // ---- AGG: rowsum + g-th j-quarter partials for 4 rows
  { const int w = t >> 6, lane = t & 63;
    if (w < 4) {
      float s = adjs[w][lane] + adjs[w][lane + 64] + adjs[w][lane + 128] + adjs[w][lane + 192];
#pragma unroll
      for (int off = 32; off; off >>= 1) s += __shfl_down(s, off);
      if (lane == 0) rs[w] = s;
    } }
  { float acc[4] = {0.f,0.f,0.f,0.f};
    const float* xjp = xj + ((size_t)b * NN + g * 64) * DD + c;
#pragma unroll
    for (int jj = 0; jj < 64; ++jj) {
      const float xv = xjp[(size_t)jj * DD];
#pragma unroll
      for (int r = 0; r < 4; ++r)
        acc[r] = fmaf(adjs[r][g * 64 + jj], fmaxf(xiv[r] + xv, 0.f), acc[r]);
    }
#pragma unroll
    for (int r = 0; r < 4; ++r) red[r][g][c] = acc[r]; }
  __syncthreads();

  // ---- F0: hs = reduce(red)
  hs[g][c] = RED4;
  __syncthreads();

  // ---- P1: red = hs @ ew2
  { float a[4] = {0.f,0.f,0.f,0.f};
    mm4(hs, W, k0, c, a);
#pragma unroll
    for (int r = 0; r < 4; ++r) red[r][g][c] = a[r]; }
  __syncthreads();

  // ---- F1: ags = reduce + rs*eb2 ; stage nw1a (ew2 dead)
  ags[g][c] = RED4 + rs[g] * eb2[c];
  STAGE(nw1);
  __syncthreads();

  // ---- P2: red = xs @ nw1a
  { float a[4] = {0.f,0.f,0.f,0.f};
    mm4(xs, W, k0, c, a);
#pragma unroll
    for (int r = 0; r < 4; ++r) red[r][g][c] = a[r]; }
  __syncthreads();

  // ---- F2: hs := t2 = reduce ; stage nw1b
  hs[g][c] = RED4;
  STAGE(nw1 + DD * DD);
  __syncthreads();

  // ---- P3: red = ags @ nw1b
  { float a[4] = {0.f,0.f,0.f,0.f};
    mm4(ags, W, k0, c, a);
#pragma unroll
    for (int r = 0; r < 4; ++r) red[r][g][c] = a[r]; }
  __syncthreads();

  // ---- F3: ns = relu(t2 + reduce + nb1) ; stage nw2
  ns[g][c] = fmaxf(hs[g][c] + RED4 + nb1[c], 0.f);
  STAGE(nw2);
  __syncthreads();

  // ---- P4: red = ns @ nw2
  { float a[4] = {0.f,0.f,0.f,0.f};
    mm4(ns, W, k0, c, a);
#pragma unroll
    for (int r = 0; r < 4; ++r) red[r][g][c] = a[r]; }
  __syncthreads();

  // ---- F4: x' = x + reduce + nb2 -> xout (+ os) ; stage ew1n_a
  { const float xo = xs[g][c] + RED4 + nb2[c];
    xout[(size_t)(r0 + g) * DD + c] = xo;
    os[g][c] = xo; }
  if (!has_next) return;
  STAGE(ew1n);
  __syncthreads();

  // ---- P5: red = x' @ ew1n_a
  { float a[4] = {0.f,0.f,0.f,0.f};
    mm4(os, W, k0, c, a);
#pragma unroll
    for (int r = 0; r < 4; ++r) red[r][g][c] = a[r]; }
  __syncthreads();

  // ---- F5: xi_next ; stage ew1n_b
  xin_[(size_t)(r0 + g) * DD + c] = RED4 + eb1n[c];
  STAGE(ew1n + DD * DD);
  __syncthreads();

  // ---- P6: red = x' @ ew1n_b
  { float a[4] = {0.f,0.f,0.f,0.f};
    mm4(os, W, k0, c, a);
#pragma unroll
    for (int r = 0; r < 4; ++r) red[r][g][c] = a[r]; }
  __syncthreads();

  // ---- F6: xj_next
  xjn[(size_t)(r0 + g) * DD + c] = RED4;
}

extern "C" void kernel_launch(void* const* d_in, const int* in_sizes, int n_in,
                              void* d_out, int out_size, void* d_ws, size_t ws_size,
                              hipStream_t stream) {
  const float* x0  = (const float*)d_in[0];
  const float* adj = (const float*)d_in[1];
  const float* ew1 = (const float*)d_in[2];
  const float* eb1 = (const float*)d_in[3];
  const float* ew2 = (const float*)d_in[4];
  const float* eb2 = (const float*)d_in[5];
  const float* nw1 = (const float*)d_in[6];
  const float* nb1 = (const float*)d_in[7];
  const float* nw2 = (const float*)d_in[8];
  const float* nb2 = (const float*)d_in[9];
  float* out = (float*)d_out;
  float* ws  = (float*)d_ws;

  float* xi0 = ws;                // 131072 floats each
  float* xj0 = ws + 131072;
  float* xi1 = ws + 262144;
  float* xj1 = ws + 393216;
  float* xA  = ws + 524288;
  float* xB  = ws + 655360;

  kproj<<<256, 512, 0, stream>>>(x0, ew1, eb1, xi0, xj0);

  const float* xins[3]  = {x0, xA, xB};
  float*       xouts[3] = {xA, xB, out};
  float*       xis[2] = {xi0, xi1};
  float*       xjs[2] = {xj0, xj1};
  for (int l = 0; l < 3; ++l) {
    const int cur = l & 1, nxt = cur ^ 1;
    const int ln = (l + 1 < 3) ? (l + 1) : 0;  // dummy for last layer (unused)
    klayer<<<256, 512, 0, stream>>>(
        xins[l], adj, xis[cur], xjs[cur],
        ew2 + l * DD * DD, eb2 + l * DD,
        nw1 + l * 2 * DD * DD, nb1 + l * DD,
        nw2 + l * DD * DD, nb2 + l * DD,
        xouts[l],
        ew1 + ln * 2 * DD * DD, eb1 + ln * DD,
        xis[nxt], xjs[nxt], (l + 1 < 3) ? 1 : 0);
  }
}